// Round 3
// baseline (624.095 us; speedup 1.0000x reference)
//
#include <hip/hip_runtime.h>

#define C_NUM 1000
#define D_DIM 128
#define MOMENTUM 0.9f
#define KCHUNKS 32      // blocks per class in the partial reduce
#define SLICE 256       // order entries staged to LDS per pass

// ws layout (4-byte words):
//   [0]            counts[C]
//   [C]            offsets[C]
//   [2C]           cursor[C]
//   [3C]           sums[C*D]   (float)
//   [3C + C*D]     order[N]

__global__ void zero_ws_words_kernel(int* __restrict__ ws, int n) {
    int i = blockIdx.x * blockDim.x + threadIdx.x;
    if (i < n) ws[i] = 0;
}

__global__ void hist_kernel(const int* __restrict__ labels, int n,
                            int* __restrict__ counts) {
    __shared__ int h[C_NUM];
    for (int i = threadIdx.x; i < C_NUM; i += blockDim.x) h[i] = 0;
    __syncthreads();
    int idx = blockIdx.x * blockDim.x + threadIdx.x;
    int stride = gridDim.x * blockDim.x;
    for (int i = idx; i < n; i += stride) atomicAdd(&h[labels[i]], 1);
    __syncthreads();
    for (int i = threadIdx.x; i < C_NUM; i += blockDim.x) {
        int v = h[i];
        if (v) atomicAdd(&counts[i], v);
    }
}

__global__ void scan_kernel(const int* __restrict__ counts,
                            int* __restrict__ offsets,
                            int* __restrict__ cursor) {
    __shared__ int s[1024];
    int t = threadIdx.x;
    int c = (t < C_NUM) ? counts[t] : 0;
    s[t] = c;
    __syncthreads();
    for (int d = 1; d < 1024; d <<= 1) {
        int v = (t >= d) ? s[t - d] : 0;
        __syncthreads();
        s[t] += v;
        __syncthreads();
    }
    if (t < C_NUM) {
        int off = s[t] - c;   // exclusive
        offsets[t] = off;
        cursor[t] = off;
    }
}

__global__ void build_order_kernel(const int* __restrict__ labels, int n,
                                   int* __restrict__ cursor,
                                   int* __restrict__ order) {
    int idx = blockIdx.x * blockDim.x + threadIdx.x;
    int stride = gridDim.x * blockDim.x;
    for (int i = idx; i < n; i += stride) {
        int lab = labels[i];
        int pos = atomicAdd(&cursor[lab], 1);
        order[pos] = i;
    }
}

__global__ __launch_bounds__(256) void partial_reduce_kernel(
        const float4* __restrict__ feat4, const int* __restrict__ order,
        const int* __restrict__ counts, const int* __restrict__ offsets,
        float* __restrict__ sums) {
    int c = blockIdx.x >> 5;          // / KCHUNKS
    int k = blockIdx.x & (KCHUNKS - 1);
    int cnt = counts[c];
    if (cnt == 0) return;             // uniform
    int off = offsets[c];
    int len = (cnt + KCHUNKS - 1) / KCHUNKS;
    int start = off + k * len;
    int end = min(start + len, off + cnt);
    if (start >= end) return;         // uniform

    int tid = threadIdx.x;
    int sub = tid >> 5;               // 0..7
    int q = tid & 31;                 // float4 lane within row

    __shared__ int ord[SLICE];
    float4 acc = make_float4(0.f, 0.f, 0.f, 0.f);

    for (int base = start; base < end; base += SLICE) {
        int m = min(SLICE, end - base);
        if (tid < m) ord[tid] = order[base + tid];
        __syncthreads();
        int i = sub;
        // 4 rows in flight per subgroup: addresses all known from LDS
        for (; i + 24 < m; i += 32) {
            int r0 = ord[i], r1 = ord[i + 8], r2 = ord[i + 16], r3 = ord[i + 24];
            float4 v0 = feat4[(long)r0 * 32 + q];
            float4 v1 = feat4[(long)r1 * 32 + q];
            float4 v2 = feat4[(long)r2 * 32 + q];
            float4 v3 = feat4[(long)r3 * 32 + q];
            acc.x += (v0.x + v1.x) + (v2.x + v3.x);
            acc.y += (v0.y + v1.y) + (v2.y + v3.y);
            acc.z += (v0.z + v1.z) + (v2.z + v3.z);
            acc.w += (v0.w + v1.w) + (v2.w + v3.w);
        }
        for (; i < m; i += 8) {
            int r = ord[i];
            float4 v = feat4[(long)r * 32 + q];
            acc.x += v.x; acc.y += v.y; acc.z += v.z; acc.w += v.w;
        }
        __syncthreads();
    }

    __shared__ float4 lds4[256];
    lds4[sub * 32 + q] = acc;
    __syncthreads();
    if (tid < D_DIM) {
        const float* lds = (const float*)lds4;
        float s = 0.f;
        #pragma unroll
        for (int g = 0; g < 8; ++g) s += lds[g * D_DIM + tid];
        atomicAdd(&sums[c * D_DIM + tid], s);
    }
}

__global__ void finalize_kernel(const float* __restrict__ prototypes,
                                const float* __restrict__ sums,
                                const int* __restrict__ counts,
                                float* __restrict__ out) {
    __shared__ float red[D_DIM];
    int c = blockIdx.x;
    int d = threadIdx.x;
    float proto = prototypes[c * D_DIM + d];
    red[d] = proto;
    __syncthreads();
    for (int s = 64; s > 0; s >>= 1) {
        if (d < s) red[d] += red[d + s];
        __syncthreads();
    }
    float rowsum = red[0];
    int cnt = counts[c];
    float mean = sums[c * D_DIM + d] / (float)max(cnt, 1);
    float ema = MOMENTUM * proto + (1.0f - MOMENTUM) * mean;
    float res = (cnt > 0) ? ((rowsum == 0.0f) ? mean : ema) : proto;
    out[c * D_DIM + d] = res;
}

// ===================== fallback (round-1 atomic path) =====================
__global__ void scatter_kernel(const float4* __restrict__ feat4,
                               const int* __restrict__ labels,
                               float* __restrict__ sums, long total4) {
    long idx = (long)blockIdx.x * blockDim.x + threadIdx.x;
    long stride = (long)gridDim.x * blockDim.x;
    for (long i = idx; i < total4; i += stride) {
        float4 v = feat4[i];
        int row = (int)(i >> 5);
        int q = (int)(i & 31);
        int lab = labels[row];
        float* dst = sums + lab * D_DIM + q * 4;
        atomicAdd(dst + 0, v.x);
        atomicAdd(dst + 1, v.y);
        atomicAdd(dst + 2, v.z);
        atomicAdd(dst + 3, v.w);
    }
}

// =========================================================================
extern "C" void kernel_launch(void* const* d_in, const int* in_sizes, int n_in,
                              void* d_out, int out_size, void* d_ws, size_t ws_size,
                              hipStream_t stream) {
    const float* features   = (const float*)d_in[0];
    const int*   labels     = (const int*)d_in[1];
    const float* prototypes = (const float*)d_in[2];
    float* out = (float*)d_out;
    int n = in_sizes[1];

    int* counts  = (int*)d_ws;
    int* offsets = counts + C_NUM;
    int* cursor  = offsets + C_NUM;
    float* sums  = (float*)(cursor + C_NUM);
    int* order   = (int*)(sums + C_NUM * D_DIM);

    size_t need = (size_t)(3 * C_NUM + C_NUM * D_DIM + n) * sizeof(int);
    if (ws_size >= need) {
        // zero counts + sums (cursor/offsets set by scan)
        int zero_n = C_NUM + C_NUM * D_DIM;
        zero_ws_words_kernel<<<(zero_n + 255) / 256, 256, 0, stream>>>(counts, C_NUM);
        zero_ws_words_kernel<<<(C_NUM * D_DIM + 255) / 256, 256, 0, stream>>>((int*)sums, C_NUM * D_DIM);
        (void)zero_n;

        hist_kernel<<<512, 256, 0, stream>>>(labels, n, counts);
        scan_kernel<<<1, 1024, 0, stream>>>(counts, offsets, cursor);
        build_order_kernel<<<1024, 256, 0, stream>>>(labels, n, cursor, order);
        partial_reduce_kernel<<<C_NUM * KCHUNKS, 256, 0, stream>>>(
            (const float4*)features, order, counts, offsets, sums);
        finalize_kernel<<<C_NUM, D_DIM, 0, stream>>>(prototypes, sums, counts, out);
    } else {
        // fallback: atomic scatter path (needs (C*D + C) words)
        float* fsums = (float*)d_ws;
        int* fcounts = (int*)(fsums + C_NUM * D_DIM);
        int zero_n = C_NUM * D_DIM + C_NUM;
        zero_ws_words_kernel<<<(zero_n + 255) / 256, 256, 0, stream>>>((int*)d_ws, zero_n);
        hist_kernel<<<512, 256, 0, stream>>>(labels, n, fcounts);
        long total4 = (long)n * (D_DIM / 4);
        scatter_kernel<<<2048, 256, 0, stream>>>((const float4*)features, labels, fsums, total4);
        finalize_kernel<<<C_NUM, D_DIM, 0, stream>>>(prototypes, fsums, fcounts, out);
    }
}

// Round 4
// 264.147 us; speedup vs baseline: 2.3627x; 2.3627x over previous
//
#include <hip/hip_runtime.h>

#define C_NUM 1000
#define D_DIM 128
#define MOMENTUM 0.9f
#define KCHUNKS 32      // blocks per class in the partial reduce
#define NBLK 1024       // partition chunks over N
#define SLICE 256       // order entries staged to LDS per pass

// ws layout (4-byte words):
//   [0]                 counts[C]
//   [C]                 offsets[C]
//   [2C]                mat[C * NBLK]          per-(class,chunk) counts -> excl. prefix
//   [2C + C*NBLK]       sums_part[K * C * D]   (float)
//   [... + K*C*D]       order[N]

// ---------- phase 1: per-chunk class histogram ----------
__global__ __launch_bounds__(256) void chunk_hist_kernel(
        const int* __restrict__ labels, int n, int* __restrict__ mat) {
    __shared__ int h[C_NUM];
    int b = blockIdx.x;
    int chunk = (n + NBLK - 1) / NBLK;
    int start = b * chunk, end = min(start + chunk, n);
    for (int i = threadIdx.x; i < C_NUM; i += 256) h[i] = 0;
    __syncthreads();
    for (int i = start + threadIdx.x; i < end; i += 256)
        atomicAdd(&h[labels[i]], 1);
    __syncthreads();
    for (int c = threadIdx.x; c < C_NUM; c += 256)
        mat[c * NBLK + b] = h[c];
}

// ---------- phase 2: per-class exclusive scan over chunks ----------
__global__ __launch_bounds__(256) void scan_mat_kernel(
        int* __restrict__ mat, int* __restrict__ counts) {
    __shared__ int ts[256];
    int c = blockIdx.x;
    int t = threadIdx.x;
    int* row = mat + c * NBLK;
    int4 v = ((int4*)row)[t];
    int s0 = v.x, s1 = s0 + v.y, s2 = s1 + v.z, s3 = s2 + v.w;
    ts[t] = s3;
    __syncthreads();
    for (int d = 1; d < 256; d <<= 1) {
        int val = (t >= d) ? ts[t - d] : 0;
        __syncthreads();
        ts[t] += val;
        __syncthreads();
    }
    int base = (t > 0) ? ts[t - 1] : 0;
    int4 o;
    o.x = base;
    o.y = base + s0;
    o.z = base + s1;
    o.w = base + s2;
    ((int4*)row)[t] = o;
    if (t == 255) counts[c] = ts[255];
}

// ---------- phase 2b: class-level exclusive offsets ----------
__global__ void scan_offsets_kernel(const int* __restrict__ counts,
                                    int* __restrict__ offsets) {
    __shared__ int s[1024];
    int t = threadIdx.x;
    int c = (t < C_NUM) ? counts[t] : 0;
    s[t] = c;
    __syncthreads();
    for (int d = 1; d < 1024; d <<= 1) {
        int v = (t >= d) ? s[t - d] : 0;
        __syncthreads();
        s[t] += v;
        __syncthreads();
    }
    if (t < C_NUM) offsets[t] = s[t] - c;   // exclusive
}

// ---------- phase 3: place indices (LDS cursors, no global atomics) ----------
__global__ __launch_bounds__(256) void place_kernel(
        const int* __restrict__ labels, int n,
        const int* __restrict__ mat, const int* __restrict__ offsets,
        int* __restrict__ order) {
    __shared__ int cur[C_NUM];
    int b = blockIdx.x;
    int chunk = (n + NBLK - 1) / NBLK;
    int start = b * chunk, end = min(start + chunk, n);
    for (int c = threadIdx.x; c < C_NUM; c += 256)
        cur[c] = offsets[c] + mat[c * NBLK + b];
    __syncthreads();
    for (int i = start + threadIdx.x; i < end; i += 256) {
        int lab = labels[i];
        int pos = atomicAdd(&cur[lab], 1);
        order[pos] = i;
    }
}

// ---------- phase 4: chunked class gather-reduce, plain slice writes ----------
__global__ __launch_bounds__(256) void partial_reduce_kernel(
        const float4* __restrict__ feat4, const int* __restrict__ order,
        const int* __restrict__ counts, const int* __restrict__ offsets,
        float* __restrict__ sums_part) {
    int c = blockIdx.x >> 5;          // / KCHUNKS
    int k = blockIdx.x & (KCHUNKS - 1);
    int cnt = counts[c];
    int off = offsets[c];
    int len = (cnt + KCHUNKS - 1) / KCHUNKS;
    int start = off + k * len;
    int end = min(start + len, off + cnt);

    int tid = threadIdx.x;
    int sub = tid >> 5;               // 0..7
    int q = tid & 31;                 // float4 lane within row

    __shared__ int ord[SLICE];
    float4 acc = make_float4(0.f, 0.f, 0.f, 0.f);

    for (int base = start; base < end; base += SLICE) {
        int m = min(SLICE, end - base);
        if (tid < m) ord[tid] = order[base + tid];
        __syncthreads();
        int i = sub;
        for (; i + 24 < m; i += 32) {
            int r0 = ord[i], r1 = ord[i + 8], r2 = ord[i + 16], r3 = ord[i + 24];
            float4 v0 = feat4[(long)r0 * 32 + q];
            float4 v1 = feat4[(long)r1 * 32 + q];
            float4 v2 = feat4[(long)r2 * 32 + q];
            float4 v3 = feat4[(long)r3 * 32 + q];
            acc.x += (v0.x + v1.x) + (v2.x + v3.x);
            acc.y += (v0.y + v1.y) + (v2.y + v3.y);
            acc.z += (v0.z + v1.z) + (v2.z + v3.z);
            acc.w += (v0.w + v1.w) + (v2.w + v3.w);
        }
        for (; i < m; i += 8) {
            int r = ord[i];
            float4 v = feat4[(long)r * 32 + q];
            acc.x += v.x; acc.y += v.y; acc.z += v.z; acc.w += v.w;
        }
        __syncthreads();
    }

    __shared__ float4 lds4[256];
    lds4[tid] = acc;
    __syncthreads();
    if (tid < D_DIM) {
        const float* lds = (const float*)lds4;
        float s = 0.f;
        #pragma unroll
        for (int g = 0; g < 8; ++g) s += lds[g * D_DIM + tid];
        sums_part[((long)k * C_NUM + c) * D_DIM + tid] = s;  // plain store
    }
}

// ---------- phase 5: reduce slices + EMA epilogue ----------
__global__ __launch_bounds__(128) void finalize_slices_kernel(
        const float* __restrict__ prototypes, const float* __restrict__ sums_part,
        const int* __restrict__ counts, float* __restrict__ out) {
    __shared__ float red[D_DIM];
    int c = blockIdx.x, d = threadIdx.x;
    float s = 0.f;
    #pragma unroll 8
    for (int k = 0; k < KCHUNKS; ++k)
        s += sums_part[((long)k * C_NUM + c) * D_DIM + d];
    float proto = prototypes[c * D_DIM + d];
    red[d] = proto;
    __syncthreads();
    for (int t = 64; t > 0; t >>= 1) {
        if (d < t) red[d] += red[d + t];
        __syncthreads();
    }
    float rowsum = red[0];
    int cnt = counts[c];
    float mean = s / (float)max(cnt, 1);
    float ema = MOMENTUM * proto + (1.f - MOMENTUM) * mean;
    out[c * D_DIM + d] = (cnt > 0) ? ((rowsum == 0.f) ? mean : ema) : proto;
}

// ===================== fallback (atomic path, small ws) =====================
__global__ void zero_ws_words_kernel(int* __restrict__ ws, int n) {
    int i = blockIdx.x * blockDim.x + threadIdx.x;
    if (i < n) ws[i] = 0;
}

__global__ void hist_kernel(const int* __restrict__ labels, int n,
                            int* __restrict__ counts) {
    __shared__ int h[C_NUM];
    for (int i = threadIdx.x; i < C_NUM; i += blockDim.x) h[i] = 0;
    __syncthreads();
    int idx = blockIdx.x * blockDim.x + threadIdx.x;
    int stride = gridDim.x * blockDim.x;
    for (int i = idx; i < n; i += stride) atomicAdd(&h[labels[i]], 1);
    __syncthreads();
    for (int i = threadIdx.x; i < C_NUM; i += blockDim.x) {
        int v = h[i];
        if (v) atomicAdd(&counts[i], v);
    }
}

__global__ void scatter_kernel(const float4* __restrict__ feat4,
                               const int* __restrict__ labels,
                               float* __restrict__ sums, long total4) {
    long idx = (long)blockIdx.x * blockDim.x + threadIdx.x;
    long stride = (long)gridDim.x * blockDim.x;
    for (long i = idx; i < total4; i += stride) {
        float4 v = feat4[i];
        int row = (int)(i >> 5);
        int q = (int)(i & 31);
        int lab = labels[row];
        float* dst = sums + lab * D_DIM + q * 4;
        atomicAdd(dst + 0, v.x);
        atomicAdd(dst + 1, v.y);
        atomicAdd(dst + 2, v.z);
        atomicAdd(dst + 3, v.w);
    }
}

__global__ void finalize_kernel(const float* __restrict__ prototypes,
                                const float* __restrict__ sums,
                                const int* __restrict__ counts,
                                float* __restrict__ out) {
    __shared__ float red[D_DIM];
    int c = blockIdx.x;
    int d = threadIdx.x;
    float proto = prototypes[c * D_DIM + d];
    red[d] = proto;
    __syncthreads();
    for (int s = 64; s > 0; s >>= 1) {
        if (d < s) red[d] += red[d + s];
        __syncthreads();
    }
    float rowsum = red[0];
    int cnt = counts[c];
    float mean = sums[c * D_DIM + d] / (float)max(cnt, 1);
    float ema = MOMENTUM * proto + (1.0f - MOMENTUM) * mean;
    out[c * D_DIM + d] = (cnt > 0) ? ((rowsum == 0.0f) ? mean : ema) : proto;
}

// =========================================================================
extern "C" void kernel_launch(void* const* d_in, const int* in_sizes, int n_in,
                              void* d_out, int out_size, void* d_ws, size_t ws_size,
                              hipStream_t stream) {
    const float* features   = (const float*)d_in[0];
    const int*   labels     = (const int*)d_in[1];
    const float* prototypes = (const float*)d_in[2];
    float* out = (float*)d_out;
    int n = in_sizes[1];

    int* counts     = (int*)d_ws;
    int* offsets    = counts + C_NUM;
    int* mat        = offsets + C_NUM;
    float* sums_part = (float*)(mat + (size_t)C_NUM * NBLK);
    int* order      = (int*)(sums_part + (size_t)KCHUNKS * C_NUM * D_DIM);

    size_t need = ((size_t)2 * C_NUM + (size_t)C_NUM * NBLK +
                   (size_t)KCHUNKS * C_NUM * D_DIM + (size_t)n) * sizeof(int);
    if (ws_size >= need) {
        chunk_hist_kernel<<<NBLK, 256, 0, stream>>>(labels, n, mat);
        scan_mat_kernel<<<C_NUM, 256, 0, stream>>>(mat, counts);
        scan_offsets_kernel<<<1, 1024, 0, stream>>>(counts, offsets);
        place_kernel<<<NBLK, 256, 0, stream>>>(labels, n, mat, offsets, order);
        partial_reduce_kernel<<<C_NUM * KCHUNKS, 256, 0, stream>>>(
            (const float4*)features, order, counts, offsets, sums_part);
        finalize_slices_kernel<<<C_NUM, D_DIM, 0, stream>>>(
            prototypes, sums_part, counts, out);
    } else {
        float* fsums = (float*)d_ws;
        int* fcounts = (int*)(fsums + C_NUM * D_DIM);
        int zero_n = C_NUM * D_DIM + C_NUM;
        zero_ws_words_kernel<<<(zero_n + 255) / 256, 256, 0, stream>>>((int*)d_ws, zero_n);
        hist_kernel<<<512, 256, 0, stream>>>(labels, n, fcounts);
        long total4 = (long)n * (D_DIM / 4);
        scatter_kernel<<<2048, 256, 0, stream>>>((const float4*)features, labels, fsums, total4);
        finalize_kernel<<<C_NUM, D_DIM, 0, stream>>>(prototypes, fsums, fcounts, out);
    }
}